// Round 3
// baseline (8523.353 us; speedup 1.0000x reference)
//
#include <hip/hip_runtime.h>
#include <cstdint>
#include <cstddef>

// Problem constants (LSTM_62173946577315): T=256, B=128, E=1024, H=1024.
#define Tn 256
#define Bn 128
#define En 1024
#define Hn 1024
#define NG 4096   // 4*H gate rows, order [g,i,f,o]
#define GRP 8     // independent batch groups (16 rows each)
#define GBLK 64   // blocks per group

typedef __bf16 bf16;
typedef __bf16 bf16x8 __attribute__((ext_vector_type(8)));
typedef __bf16 bf16x4 __attribute__((ext_vector_type(4)));
typedef float  f32x4  __attribute__((ext_vector_type(4)));

typedef __attribute__((address_space(1))) void gvoid;
typedef __attribute__((address_space(3))) void lvoid;

__device__ __forceinline__ float sigmoidf_(float x) {
  return 1.0f / (1.0f + __expf(-x));
}

// ---------------------------------------------------------------------------
// prep_w: split W_* (H x (E+H)) fp32 into Wx[4][H][E], Wh[4][H][H] bf16
// (row-major over k) and concatenate biases into bias[4096] fp32.
// ---------------------------------------------------------------------------
__global__ __launch_bounds__(256) void prep_w(
    const float* __restrict__ Wg, const float* __restrict__ Wi,
    const float* __restrict__ Wf, const float* __restrict__ Wo,
    const float* __restrict__ bg, const float* __restrict__ bi,
    const float* __restrict__ bff, const float* __restrict__ bo,
    bf16* __restrict__ Wx, bf16* __restrict__ Wh, float* __restrict__ bias)
{
  int idx = blockIdx.x * 256 + threadIdx.x;   // 0 .. 4*1024*1024-1
  int g = idx >> 20;
  int r = idx & 0xFFFFF;                      // u*1024 + k
  int u = r >> 10;
  int k = r & 1023;
  const float* Ws = (g == 0) ? Wg : (g == 1) ? Wi : (g == 2) ? Wf : Wo;
  size_t src = (size_t)u * (En + Hn) + k;
  Wx[idx] = (bf16)Ws[src];        // x-part: cols [0, E)
  Wh[idx] = (bf16)Ws[src + En];   // h-part: cols [E, E+H)
  if (idx < NG) {
    int gg = idx >> 10, uu = idx & 1023;
    const float* bs = (gg == 0) ? bg : (gg == 1) ? bi : (gg == 2) ? bff : bo;
    bias[idx] = bs[uu];
  }
}

// ---------------------------------------------------------------------------
// conv_x: embeds fp32 (T*B*E) -> bf16, vectorized x4.
// ---------------------------------------------------------------------------
__global__ __launch_bounds__(256) void conv_x(const float* __restrict__ X,
                                              bf16* __restrict__ Xb)
{
  int idx = blockIdx.x * 256 + threadIdx.x;   // per float4
  f32x4 v = ((const f32x4*)X)[idx];
  bf16x4 o;
  o[0] = (bf16)v[0]; o[1] = (bf16)v[1]; o[2] = (bf16)v[2]; o[3] = (bf16)v[3];
  ((bf16x4*)Xb)[idx] = o;
}

// ---------------------------------------------------------------------------
// zx_gemm (m97-style): ZX[m][n] = Xb[m+128][:] . Wx[n][:] + bias[n].
// M=32640 (255 t-blocks of 128), N=4096, K=1024. 128x128 block tile,
// 4 waves in 2x2, each wave 64x64 (4x4 mfma 16x16x32). BK=32, single-buffer
// LDS staged via global_load_lds width=16.
// ---------------------------------------------------------------------------
__global__ __launch_bounds__(256) void zx_gemm(
    const bf16* __restrict__ Xb, const bf16* __restrict__ Wx,
    const float* __restrict__ bias, bf16* __restrict__ zx)
{
  const int tid  = threadIdx.x;
  const int lane = tid & 63;
  const int w    = tid >> 6;
  const int wm = w >> 1, wn = w & 1;
  const int l15 = lane & 15, lq = lane >> 4;
  const int n0 = blockIdx.x * 128;
  const int m0 = blockIdx.y * 128;      // zx row
  const int mg = 128 + m0;              // Xb row (skip t=0)

  __shared__ bf16 As[128 * 32];
  __shared__ bf16 Bs[128 * 32];

  const f32x4 zero4 = {0.f, 0.f, 0.f, 0.f};
  f32x4 acc[4][4];
  #pragma unroll
  for (int mt = 0; mt < 4; ++mt)
    #pragma unroll
    for (int nt = 0; nt < 4; ++nt) acc[mt][nt] = zero4;

  const int srow = lane >> 2;           // 0..15 row within a 16-row chunk
  const int schk = lane & 3;            // 16B chunk within BK=32 row

  for (int kc = 0; kc < 32; ++kc) {
    const int k0 = kc * 32;
    #pragma unroll
    for (int j = 0; j < 2; ++j) {
      int rloc = w * 32 + j * 16;       // wave-uniform row base
      const bf16* asrc = Xb + (size_t)(mg + rloc + srow) * En + k0 + schk * 8;
      __builtin_amdgcn_global_load_lds((const gvoid*)asrc,
                                       (lvoid*)&As[rloc * 32], 16, 0, 0);
      const bf16* bsrc = Wx + (size_t)(n0 + rloc + srow) * En + k0 + schk * 8;
      __builtin_amdgcn_global_load_lds((const gvoid*)bsrc,
                                       (lvoid*)&Bs[rloc * 32], 16, 0, 0);
    }
    __syncthreads();

    bf16x8 af[4], bfm[4];
    #pragma unroll
    for (int mt = 0; mt < 4; ++mt)
      af[mt] = *(const bf16x8*)&As[(wm * 64 + mt * 16 + l15) * 32 + lq * 8];
    #pragma unroll
    for (int nt = 0; nt < 4; ++nt)
      bfm[nt] = *(const bf16x8*)&Bs[(wn * 64 + nt * 16 + l15) * 32 + lq * 8];
    #pragma unroll
    for (int mt = 0; mt < 4; ++mt)
      #pragma unroll
      for (int nt = 0; nt < 4; ++nt)
        acc[mt][nt] = __builtin_amdgcn_mfma_f32_16x16x32_bf16(
            af[mt], bfm[nt], acc[mt][nt], 0, 0, 0);
    __syncthreads();
  }

  float bv[4];
  #pragma unroll
  for (int nt = 0; nt < 4; ++nt)
    bv[nt] = bias[n0 + wn * 64 + nt * 16 + l15];
  #pragma unroll
  for (int mt = 0; mt < 4; ++mt)
    #pragma unroll
    for (int nt = 0; nt < 4; ++nt)
      #pragma unroll
      for (int i = 0; i < 4; ++i) {
        int m = m0 + wm * 64 + mt * 16 + lq * 4 + i;  // C row = lq*4+i
        int n = n0 + wn * 64 + nt * 16 + l15;         // C col = l15
        zx[(size_t)m * NG + n] = (bf16)(acc[mt][nt][i] + bv[nt]);
      }
}

// ---------------------------------------------------------------------------
// lstm_persist v2: 512 blocks (2/CU), 8 INDEPENDENT groups of 64 blocks.
// Group gid = blockIdx>>6 owns batch rows [gid*16, gid*16+16) — batch rows
// are independent recurrences, so barriers are per-group (64 arrivals).
// Co-resident blocks (i, i+256) are in different groups -> barrier stall of
// one group overlaps compute of the other.
// Block = 16 units x 4 gates; wave = gate, Wh slice (16x1024) in 128 VGPRs.
// h tile (16x1024) staged to LDS via ds_write with XOR chunk swizzle
// (chunk^(row&7)) -> 2-way-max bank aliasing on ds_read_b128 (free).
// ---------------------------------------------------------------------------
__global__ __launch_bounds__(256, 2) void lstm_persist(
    const bf16* __restrict__ Wh,    // [4][1024][1024]
    const bf16* __restrict__ zx,    // [255*128][4096] (bias folded in)
    bf16* __restrict__ hb0,         // ping [128][1024]
    bf16* __restrict__ hb1,         // pong [128][1024]
    float* __restrict__ out,        // [256][128][1024]
    unsigned int* __restrict__ bar) // [8][256] zero-initialized slots
{
  const int tid  = threadIdx.x;
  const int lane = tid & 63;
  const int g    = tid >> 6;          // wave index == gate
  const int l15  = lane & 15;
  const int lq   = lane >> 4;
  const int gid  = blockIdx.x >> 6;   // batch group
  const int wg   = blockIdx.x & 63;   // unit tile within group
  const int row0 = gid * 16;          // batch rows [row0, row0+16)
  const int u0   = wg * 16;

  __shared__ bf16  hs[16 * 1024];     // 32 KB, swizzled chunks
  __shared__ float zs[4][16][17];     // 4.4 KB gate exchange

  // --- Preload this wave's Wh slice into registers: 16 n x 1024 k ---------
  bf16x8 wfrag[32];
  {
    const bf16* wp = Wh + ((size_t)(g * Hn + u0 + l15)) * Hn + lq * 8;
    #pragma unroll
    for (int ks = 0; ks < 32; ++ks)
      wfrag[ks] = *(const bf16x8*)(wp + ks * 32);
  }

  float creg = 0.f;                   // cell state for this thread's cell
  const int bl = tid >> 4;            // elementwise: batch-local row
  const int ul = tid & 15;            // elementwise: unit-local col
  const f32x4 zero4 = {0.f, 0.f, 0.f, 0.f};

  for (int t = 1; t < Tn; ++t) {
    const bf16* hin  = ((t - 1) & 1) ? hb1 : hb0;
    bf16*       hout = (t & 1) ? hb1 : hb0;

    // --- Stage h(t-1) rows [row0,row0+16) into LDS, XOR-swizzled ---------
    const bf16* hinb = hin + (size_t)row0 * Hn;
    #pragma unroll
    for (int j = 0; j < 8; ++j) {
      int f  = tid + 256 * j;         // flat 16B-chunk id, 0..2047
      int r  = f >> 7;                // row 0..15
      int ch = f & 127;               // chunk 0..127
      bf16x8 v = *(const bf16x8*)(hinb + (size_t)r * Hn + ch * 8);
      *(bf16x8*)&hs[r * 1024 + (ch ^ (r & 7)) * 8] = v;
    }
    __syncthreads();

    // --- z partial = h_tile @ Wh_g^T : 32 MFMAs, split-K dual acc --------
    f32x4 acc0 = zero4, acc1 = zero4;
    #pragma unroll 8
    for (int ks = 0; ks < 16; ++ks) {
      int c0 = (2 * ks) * 4 + lq;
      int c1 = (2 * ks + 1) * 4 + lq;
      bf16x8 a0 = *(const bf16x8*)&hs[l15 * 1024 + (c0 ^ (l15 & 7)) * 8];
      bf16x8 a1 = *(const bf16x8*)&hs[l15 * 1024 + (c1 ^ (l15 & 7)) * 8];
      acc0 = __builtin_amdgcn_mfma_f32_16x16x32_bf16(a0, wfrag[2 * ks], acc0, 0, 0, 0);
      acc1 = __builtin_amdgcn_mfma_f32_16x16x32_bf16(a1, wfrag[2 * ks + 1], acc1, 0, 0, 0);
    }

    // --- Gate exchange through LDS ---------------------------------------
    #pragma unroll
    for (int i = 0; i < 4; ++i)
      zs[g][lq * 4 + i][l15] = acc0[i] + acc1[i];   // C row = lq*4+i, col = l15
    __syncthreads();

    // --- Fused elementwise: 256 cells, 1 per thread ----------------------
    {
      int b = row0 + bl;
      int u = u0 + ul;
      size_t zoff = ((size_t)(t - 1) * Bn + b) * NG;
      float zg = zs[0][bl][ul] + (float)zx[zoff + 0 * Hn + u];
      float zi = zs[1][bl][ul] + (float)zx[zoff + 1 * Hn + u];
      float zf = zs[2][bl][ul] + (float)zx[zoff + 2 * Hn + u];
      float zo = zs[3][bl][ul] + (float)zx[zoff + 3 * Hn + u];
      float gv = tanhf(zg);
      float iv = sigmoidf_(zi);
      float fv = sigmoidf_(zf);
      float ov = sigmoidf_(zo);
      float cv = fv * creg + iv * gv;
      creg = cv;
      float hv = ov * tanhf(cv);
      size_t off = (size_t)b * Hn + u;
      __builtin_nontemporal_store((bf16)hv, &hout[off]);          // keep L2 clean
      __builtin_nontemporal_store(hv, &out[(size_t)t * Bn * Hn + off]);
    }

    // --- Per-group barrier: h(t) rows visible to this group's 64 blocks --
    __syncthreads();   // all stores issued & drained (vmcnt) + zs/hs WAR
    if (t < Tn - 1) {
      if (tid == 0) {
        unsigned int* slot = &bar[gid * 256 + t];
        __hip_atomic_fetch_add(slot, 1u, __ATOMIC_RELEASE,
                               __HIP_MEMORY_SCOPE_AGENT);
        while (__hip_atomic_load(slot, __ATOMIC_RELAXED,
                                 __HIP_MEMORY_SCOPE_AGENT) < (unsigned)GBLK) {
          __builtin_amdgcn_s_sleep(2);
        }
        (void)__hip_atomic_load(slot, __ATOMIC_ACQUIRE,
                                __HIP_MEMORY_SCOPE_AGENT);
      }
      __syncthreads();
    }
  }
}

// ---------------------------------------------------------------------------
// kernel_launch
// ---------------------------------------------------------------------------
extern "C" void kernel_launch(void* const* d_in, const int* in_sizes, int n_in,
                              void* d_out, int out_size, void* d_ws, size_t ws_size,
                              hipStream_t stream) {
  const float* embeds = (const float*)d_in[0];
  const float* Wg = (const float*)d_in[1];
  const float* Wi = (const float*)d_in[2];
  const float* Wf = (const float*)d_in[3];
  const float* Wo = (const float*)d_in[4];
  const float* bg = (const float*)d_in[5];
  const float* bi = (const float*)d_in[6];
  const float* bff = (const float*)d_in[7];
  const float* bo = (const float*)d_in[8];
  float* out = (float*)d_out;

  // Workspace carve (bytes; all >=16B-aligned):
  //   Wx bf16  [4096][1024]          @ 0          (8,388,608)
  //   Wh bf16  [4096][1024]          @ 8388608    (8,388,608)
  //   bias f32 [4096]                @ 16777216   (16,384)
  //   Xb bf16  [256][128][1024]      @ 16793600   (67,108,864)
  //   zx bf16  [32640][4096]         @ 83902464   (267,386,880)
  //   h0 bf16  [128][1024]           @ 351289344  (262,144)
  //   h1 bf16  [128][1024]           @ 351551488  (262,144)
  //   bar u32  [8][256]              @ 351813632  (8,192)
  char* ws = (char*)d_ws;
  bf16*  Wx   = (bf16*)(ws + 0);
  bf16*  Wh   = (bf16*)(ws + 8388608);
  float* bias = (float*)(ws + 16777216);
  bf16*  Xb   = (bf16*)(ws + 16793600);
  bf16*  zx   = (bf16*)(ws + 83902464);
  bf16*  h0b  = (bf16*)(ws + 351289344);
  bf16*  h1b  = (bf16*)(ws + 351551488);
  unsigned int* bar = (unsigned int*)(ws + 351813632);

  // out[0] = h0 = zeros; zero h ping buffer and barrier slots.
  hipMemsetAsync(out, 0, (size_t)Bn * Hn * sizeof(float), stream);
  hipMemsetAsync(h0b, 0, (size_t)Bn * Hn * sizeof(bf16), stream);
  hipMemsetAsync(bar, 0, GRP * 256 * sizeof(unsigned int), stream);

  prep_w<<<16384, 256, 0, stream>>>(Wg, Wi, Wf, Wo, bg, bi, bff, bo, Wx, Wh, bias);
  conv_x<<<32768, 256, 0, stream>>>(embeds, Xb);
  zx_gemm<<<dim3(32, 255), 256, 0, stream>>>(Xb, Wx, bias, zx);

  void* args[] = {(void*)&Wh, (void*)&zx, (void*)&h0b, (void*)&h1b,
                  (void*)&out, (void*)&bar};
  hipLaunchCooperativeKernel((void*)lstm_persist, dim3(512), dim3(256),
                             args, 0, stream);
}